// Round 11
// baseline (1039.951 us; speedup 1.0000x reference)
//
#include <hip/hip_runtime.h>
#include <math.h>

#define Hd 128
#define Ln 64
#define Bsz 8
#define NBLK 256
#define NTHR 512
#define SLOTS 32   // blocks per batch; block s owns cells j=s (half 0) and j=s+32 (half 1)

// d_ws: T[8][64][64][128] f32 (16MB) + flags int[8][64][64] (128KB).
// Deps of cell (i,j): flags (i-1,j) and (i-1,j+1) (transitive cover).
// Each block processes its TWO same-level cells CONCURRENTLY: waves 0-3 = cell A
// (j=s), waves 4-7 = cell B (j=s+32). Per half: phase A 16 rows/wave, MFMA
// matvec with 32 cols/wave (exact 3-way bf16 split, B-frags in registers).
// 3 block-wide barriers per level; k-softmax is wave-redundant (no wave0 sync).
// All inter-block data via agent-scope relaxed atomics (LLC-coherent).

typedef __attribute__((ext_vector_type(8))) short short8v;
typedef __attribute__((ext_vector_type(4))) float f32x4;

__global__ void init_kernel(const float* __restrict__ wf, float* __restrict__ T,
                            int* __restrict__ flg) {
    int idx = blockIdx.x * 256 + threadIdx.x;   // 0..65535
    int b = idx >> 13;
    int rest = idx & 8191;
    T[(size_t)b * (Ln * Ln * Hd) + rest] = wf[idx];
    if (idx < Bsz * Ln * Ln) flg[idx] = 0;
}

__device__ __forceinline__ float2 ld_row8(const float* p) {
    unsigned long long v = __hip_atomic_load((const unsigned long long*)p,
                                             __ATOMIC_RELAXED, __HIP_MEMORY_SCOPE_AGENT);
    return __builtin_bit_cast(float2, v);
}

__device__ __forceinline__ void wait_flag(const int* p) {
    while (__hip_atomic_load(p, __ATOMIC_RELAXED, __HIP_MEMORY_SCOPE_AGENT) == 0)
        __builtin_amdgcn_s_sleep(1);
    asm volatile("" ::: "memory");
}

// exact 3-way bf16 decomposition: x == bf(a0)+bf(a1)+bf(a2)
__device__ __forceinline__ void bf_split3(float x, unsigned short& a0,
                                          unsigned short& a1, unsigned short& a2) {
    unsigned u0 = __builtin_bit_cast(unsigned, x);
    a0 = (unsigned short)(u0 >> 16);
    float f0 = __builtin_bit_cast(float, u0 & 0xffff0000u);
    float r1 = x - f0;
    unsigned u1 = __builtin_bit_cast(unsigned, r1);
    a1 = (unsigned short)(u1 >> 16);
    float f1 = __builtin_bit_cast(float, u1 & 0xffff0000u);
    float r2 = r1 - f1;
    a2 = (unsigned short)(__builtin_bit_cast(unsigned, r2) >> 16);
}

__device__ __forceinline__ float bfval(unsigned short v) {
    return __builtin_bit_cast(float, ((unsigned)v) << 16);
}

#define MFMA_BF16 __builtin_amdgcn_mfma_f32_16x16x32_bf16

// two output col-tiles (accA: cols 32wh..+16, accB: cols 32wh+16..+32) share A-frags
#define KSTEP2(SK)                                                              \
    {                                                                           \
        int offk = ((16 * ch + (ln & 15)) << 7) +                               \
                   ((((SK << 2) + (ln >> 4)) ^ (ln & 15)) << 3);                \
        short8v a0 = *(const short8v*)&sh0[offk];                               \
        short8v a1 = *(const short8v*)&sh1[offk];                               \
        short8v a2 = *(const short8v*)&sh2[offk];                               \
        accA = MFMA_BF16(a0, B0[0][SK], accA, 0, 0, 0);                         \
        accB = MFMA_BF16(a0, B0[1][SK], accB, 0, 0, 0);                         \
        accA = MFMA_BF16(a0, B1[0][SK], accA, 0, 0, 0);                         \
        accB = MFMA_BF16(a0, B1[1][SK], accB, 0, 0, 0);                         \
        accA = MFMA_BF16(a1, B0[0][SK], accA, 0, 0, 0);                         \
        accB = MFMA_BF16(a1, B0[1][SK], accB, 0, 0, 0);                         \
        accA = MFMA_BF16(a0, B2[0][SK], accA, 0, 0, 0);                         \
        accB = MFMA_BF16(a0, B2[1][SK], accB, 0, 0, 0);                         \
        accA = MFMA_BF16(a1, B1[0][SK], accA, 0, 0, 0);                         \
        accB = MFMA_BF16(a1, B1[1][SK], accB, 0, 0, 0);                         \
        accA = MFMA_BF16(a2, B0[0][SK], accA, 0, 0, 0);                         \
        accB = MFMA_BF16(a2, B0[1][SK], accB, 0, 0, 0);                         \
    }

template<int NCH>
__device__ __forceinline__ void do_level(
    int i, int j, bool valid, int b, int wh, int ln, int tid,
    const float* __restrict__ Tb, float* __restrict__ T, float* __restrict__ out,
    int* __restrict__ flgb,
    unsigned short* __restrict__ sh0, unsigned short* __restrict__ sh1,
    unsigned short* __restrict__ sh2,
    float (*pt)[Ln],
    const short8v (&B0)[2][4], const short8v (&B1)[2][4], const short8v (&B2)[2][4],
    float2 wlv, float2 wrv, float bl, float br, float bs,
    float wsc0, float wsc1, float bbc0, float bbc1)
{
    // ---- phase A: wave wh handles rows k = wh + 4r, two passes of 8 ----
    if (valid) {
        if (i >= 2) {
            wait_flag(&flgb[(i - 1) * Ln + j]);
            wait_flag(&flgb[(i - 1) * Ln + j + 1]);
        }
        #pragma unroll
        for (int pass = 0; pass < 2; ++pass) {
            float2 Lr[8], Rr[8];
            #pragma unroll
            for (int r = 0; r < 8; ++r) {
                int k = wh + 32 * pass + 4 * r;
                int kcl = k < i ? k : i - 1;
                Lr[r] = ld_row8(Tb + ((size_t)kcl * Ln + j) * Hd + 2 * ln);
                Rr[r] = ld_row8(Tb + ((size_t)(i - 1 - kcl) * Ln + (j + kcl + 1)) * Hd + 2 * ln);
            }
            float pl[8], pr[8];
            #pragma unroll
            for (int r = 0; r < 8; ++r) {
                pl[r] = Lr[r].x * wlv.x + Lr[r].y * wlv.y;
                pr[r] = Rr[r].x * wrv.x + Rr[r].y * wrv.y;
            }
            #pragma unroll
            for (int off2 = 32; off2 > 0; off2 >>= 1) {
                #pragma unroll
                for (int r = 0; r < 8; ++r) {
                    pl[r] += __shfl_xor(pl[r], off2);
                    pr[r] += __shfl_xor(pr[r], off2);
                }
            }
            #pragma unroll
            for (int r = 0; r < 8; ++r) {
                int k = wh + 32 * pass + 4 * r;
                float sl = pl[r] + bl, sr2 = pr[r] + br;
                float mm = fmaxf(sl, sr2);
                float e0 = __expf(sl - mm), e1 = __expf(sr2 - mm);
                float inv = 1.f / (e0 + e1);
                float w0 = e0 * inv, w1 = e1 * inv;
                float h0 = w0 * Lr[r].x + w1 * Rr[r].x;
                float h1 = w0 * Lr[r].y + w1 * Rr[r].y;
                unsigned short x0, x1, x2, y0, y1, y2;
                bf_split3(h0, x0, x1, x2);
                bf_split3(h1, y0, y1, y2);
                int off = (k << 7) + (((ln >> 2) ^ (k & 15)) << 3) + ((2 * ln) & 7);
                *(unsigned*)&sh0[off] = (unsigned)x0 | ((unsigned)y0 << 16);
                *(unsigned*)&sh1[off] = (unsigned)x1 | ((unsigned)y1 << 16);
                *(unsigned*)&sh2[off] = (unsigned)x2 | ((unsigned)y2 << 16);
            }
        }
    }
    __syncthreads();   // sH ready (both halves)

    // ---- MFMA matvec: wave owns cols [32wh,32wh+32) as 2 tiles ----
    const int col0 = 32 * wh + (ln & 15);
    const int col1 = col0 + 16;
    float tmp0[NCH][4], tmp1[NCH][4];
    if (valid) {
        #pragma unroll
        for (int ch = 0; ch < NCH; ++ch) {
            f32x4 accA = {0.f, 0.f, 0.f, 0.f};
            f32x4 accB = {0.f, 0.f, 0.f, 0.f};
            KSTEP2(0)
            KSTEP2(1)
            KSTEP2(2)
            KSTEP2(3)
            float p[4];
            #pragma unroll
            for (int q = 0; q < 4; ++q) {
                int row = 16 * ch + (ln >> 4) * 4 + q;   // C/D: col=lane&15, row=(lane>>4)*4+reg
                int offh0 = (row << 7) + (((col0 >> 3) ^ (row & 15)) << 3) + (col0 & 7);
                int offh1 = (row << 7) + (((col1 >> 3) ^ (row & 15)) << 3) + (col1 & 7);
                float h0 = (bfval(sh0[offh0]) + bfval(sh1[offh0])) + bfval(sh2[offh0]);
                float h1 = (bfval(sh0[offh1]) + bfval(sh1[offh1])) + bfval(sh2[offh1]);
                float t0 = fmaxf(accA[q] + bbc0, 0.f) + h0;
                float t1 = fmaxf(accB[q] + bbc1, 0.f) + h1;
                tmp0[ch][q] = t0;
                tmp1[ch][q] = t1;
                p[q] = t0 * wsc0 + t1 * wsc1;
            }
            #pragma unroll
            for (int off2 = 1; off2 <= 8; off2 <<= 1) {
                #pragma unroll
                for (int q = 0; q < 4; ++q) p[q] += __shfl_xor(p[q], off2);
            }
            if ((ln & 15) == 0) {
                #pragma unroll
                for (int q = 0; q < 4; ++q)
                    pt[wh][16 * ch + (ln >> 4) * 4 + q] = p[q];
            }
        }
    }
    __syncthreads();   // part ready (both halves)

    // ---- wave-redundant softmax over k + weighted sum + store ----
    if (valid) {
        float lgv = -INFINITY;
        if (ln < i)
            lgv = ((pt[0][ln] + pt[1][ln]) + (pt[2][ln] + pt[3][ln])) + bs;
        float M = lgv;
        #pragma unroll
        for (int off2 = 32; off2 > 0; off2 >>= 1) M = fmaxf(M, __shfl_xor(M, off2));
        M = fmaxf(M, bs);
        float e = (ln < i) ? __expf(lgv - M) : 0.f;
        float S = e;
        #pragma unroll
        for (int off2 = 32; off2 > 0; off2 >>= 1) S += __shfl_xor(S, off2);
        float den = S + (float)(Ln - i) * __expf(bs - M);

        float v0 = 0.f, v1 = 0.f;
        #pragma unroll
        for (int ch = 0; ch < NCH; ++ch) {
            #pragma unroll
            for (int q = 0; q < 4; ++q) {
                int row = 16 * ch + (ln >> 4) * 4 + q;
                float ek = __shfl(e, row);
                v0 += ek * tmp0[ch][q];
                v1 += ek * tmp1[ch][q];
            }
        }
        v0 += __shfl_xor(v0, 16); v0 += __shfl_xor(v0, 32);
        v1 += __shfl_xor(v1, 16); v1 += __shfl_xor(v1, 32);
        if (ln < 16) {
            size_t base = (((size_t)b * Ln + i) * Ln + j) * Hd;
            float r0 = v0 / den, r1 = v1 / den;
            __hip_atomic_store(&T[base + col0], r0, __ATOMIC_RELAXED,
                               __HIP_MEMORY_SCOPE_AGENT);
            __hip_atomic_store(&T[base + col1], r1, __ATOMIC_RELAXED,
                               __HIP_MEMORY_SCOPE_AGENT);
            if (i == Ln - 1) { out[b * Hd + col0] = r0; out[b * Hd + col1] = r1; }
        }
    }
    __syncthreads();   // all stores drained (vmcnt 0 per wave before barrier)
    if ((tid & 255) == 0 && valid)
        __hip_atomic_store(&flgb[i * Ln + j], 1, __ATOMIC_RELAXED,
                           __HIP_MEMORY_SCOPE_AGENT);
}

__global__ __launch_bounds__(NTHR, 2)
void glt_df(const float* __restrict__ Wl, const float* __restrict__ blp,
            const float* __restrict__ Wr, const float* __restrict__ brp,
            const float* __restrict__ Wrep, const float* __restrict__ brepp,
            const float* __restrict__ Wsv, const float* __restrict__ bsp,
            float* __restrict__ T, int* __restrict__ flg, float* __restrict__ out)
{
    __shared__ __align__(16) unsigned short sH0[2][Ln * Hd];   // 32 KB
    __shared__ __align__(16) unsigned short sH1[2][Ln * Hd];   // 32 KB
    __shared__ __align__(16) unsigned short sH2[2][Ln * Hd];   // 32 KB
    __shared__ float part[2][4][Ln];                           // 2 KB

    const int tid  = threadIdx.x;
    const int half = tid >> 8;           // 0: cell A (j=s), 1: cell B (j=s+32)
    const int wh   = (tid >> 6) & 3;     // wave within half
    const int ln   = tid & 63;
    const int b    = blockIdx.x & 7;     // XCD round-robin: batch -> XCD
    const int s    = blockIdx.x >> 3;    // slot 0..31 within batch

    // ---- B-fragments: Wrep cols [32wh,32wh+32) exact 3-way bf16, registers ----
    const int bcol = 32 * wh + (ln & 15);
    short8v B0[2][4], B1[2][4], B2[2][4];
    #pragma unroll
    for (int ct = 0; ct < 2; ++ct) {
        #pragma unroll
        for (int sk = 0; sk < 4; ++sk) {
            #pragma unroll
            for (int jx = 0; jx < 8; ++jx) {
                int k = 32 * sk + (ln >> 4) * 8 + jx;   // same k-map as A frags
                float w = Wrep[k * Hd + bcol + 16 * ct];
                unsigned short w0, w1, w2;
                bf_split3(w, w0, w1, w2);
                B0[ct][sk][jx] = (short)w0;
                B1[ct][sk][jx] = (short)w1;
                B2[ct][sk][jx] = (short)w2;
            }
        }
    }

    const float bl = blp[0], br = brp[0], bs = bsp[0];
    const float2 wlv = *(const float2*)&Wl[2 * ln];
    const float2 wrv = *(const float2*)&Wr[2 * ln];
    const float wsc0 = Wsv[bcol],      wsc1 = Wsv[bcol + 16];
    const float bbc0 = brepp[bcol],    bbc1 = brepp[bcol + 16];

    const float* Tb = T + (size_t)b * (Ln * Ln * Hd);
    int* flgb = flg + b * (Ln * Ln);

    unsigned short* sh0 = &sH0[half][0];
    unsigned short* sh1 = &sH1[half][0];
    unsigned short* sh2 = &sH2[half][0];
    float (*pt)[Ln] = part[half];

    // ---- level-by-level walk; both cells of a level run concurrently ----
    for (int i = 1; i < Ln; ++i) {
        const int j = s + (half << 5);
        const bool valid = (j < Ln - i);
        switch ((i + 15) >> 4) {
            case 1: do_level<1>(i, j, valid, b, wh, ln, tid, Tb, T, out, flgb,
                                sh0, sh1, sh2, pt, B0, B1, B2,
                                wlv, wrv, bl, br, bs, wsc0, wsc1, bbc0, bbc1); break;
            case 2: do_level<2>(i, j, valid, b, wh, ln, tid, Tb, T, out, flgb,
                                sh0, sh1, sh2, pt, B0, B1, B2,
                                wlv, wrv, bl, br, bs, wsc0, wsc1, bbc0, bbc1); break;
            case 3: do_level<3>(i, j, valid, b, wh, ln, tid, Tb, T, out, flgb,
                                sh0, sh1, sh2, pt, B0, B1, B2,
                                wlv, wrv, bl, br, bs, wsc0, wsc1, bbc0, bbc1); break;
            default: do_level<4>(i, j, valid, b, wh, ln, tid, Tb, T, out, flgb,
                                 sh0, sh1, sh2, pt, B0, B1, B2,
                                 wlv, wrv, bl, br, bs, wsc0, wsc1, bbc0, bbc1); break;
        }
    }
}

extern "C" void kernel_launch(void* const* d_in, const int* in_sizes, int n_in,
                              void* d_out, int out_size, void* d_ws, size_t ws_size,
                              hipStream_t stream)
{
    const float* wf   = (const float*)d_in[0];
    const float* Wl   = (const float*)d_in[2];
    const float* bl   = (const float*)d_in[3];
    const float* Wr   = (const float*)d_in[4];
    const float* br   = (const float*)d_in[5];
    const float* Wrep = (const float*)d_in[6];
    const float* brep = (const float*)d_in[7];
    const float* Ws   = (const float*)d_in[8];
    const float* bs   = (const float*)d_in[9];

    float* T   = (float*)d_ws;                                   // 16 MB
    int*   flg = (int*)((char*)d_ws + (size_t)Bsz * Ln * Ln * Hd * 4);
    float* out = (float*)d_out;

    init_kernel<<<256, 256, 0, stream>>>(wf, T, flg);
    glt_df<<<NBLK, NTHR, 0, stream>>>(Wl, bl, Wr, br, Wrep, brep, Ws, bs,
                                      T, flg, out);
}

// Round 12
// 633.410 us; speedup vs baseline: 1.6418x; 1.6418x over previous
//
#include <hip/hip_runtime.h>
#include <math.h>

#define Hd 128
#define Ln 64
#define Bsz 8
#define NTHR 512
#define NBLK 512   // 64 column-blocks per batch x 8 batches; 2 blocks/CU

// d_ws: T[8][64][64][128] f32 (16MB) + flags int[8][64][64] (128KB).
// COLUMN-OWNERSHIP dataflow: block (b, p) owns column j = 63-p, computes cells
// (i, j) for i = 1..p in order. Deps of (i,j): (i-1,j) = SELF (previous iter,
// no flag), (i-1,j+1) = block p-1 (one flag wait, lower blockIdx => DAG is
// ascending in blockIdx: deadlock-free under ascending dispatch, no
// co-residency requirement). Cell body = round-8-proven MFMA cell (116 VGPR,
// fits the empirical 128-cap of __launch_bounds__(512,2) spill-free).
// Matvec on MFMA with EXACT 3-way bf16 split; Wrep B-frags in registers.
// All inter-block data via agent-scope relaxed atomics (LLC-coherent).

typedef __attribute__((ext_vector_type(8))) short short8v;
typedef __attribute__((ext_vector_type(4))) float f32x4;

__global__ void init_kernel(const float* __restrict__ wf, float* __restrict__ T,
                            int* __restrict__ flg) {
    int idx = blockIdx.x * 256 + threadIdx.x;   // 0..65535
    int b = idx >> 13;
    int rest = idx & 8191;
    T[(size_t)b * (Ln * Ln * Hd) + rest] = wf[idx];
    if (idx < Bsz * Ln * Ln) flg[idx] = 0;
}

__device__ __forceinline__ float2 ld_row8(const float* p) {
    unsigned long long v = __hip_atomic_load((const unsigned long long*)p,
                                             __ATOMIC_RELAXED, __HIP_MEMORY_SCOPE_AGENT);
    return __builtin_bit_cast(float2, v);
}

__device__ __forceinline__ void wait_flag(const int* p) {
    while (__hip_atomic_load(p, __ATOMIC_RELAXED, __HIP_MEMORY_SCOPE_AGENT) == 0)
        __builtin_amdgcn_s_sleep(1);
    asm volatile("" ::: "memory");
}

// exact 3-way bf16 decomposition: x == bf(a0)+bf(a1)+bf(a2)
__device__ __forceinline__ void bf_split3(float x, unsigned short& a0,
                                          unsigned short& a1, unsigned short& a2) {
    unsigned u0 = __builtin_bit_cast(unsigned, x);
    a0 = (unsigned short)(u0 >> 16);
    float f0 = __builtin_bit_cast(float, u0 & 0xffff0000u);
    float r1 = x - f0;
    unsigned u1 = __builtin_bit_cast(unsigned, r1);
    a1 = (unsigned short)(u1 >> 16);
    float f1 = __builtin_bit_cast(float, u1 & 0xffff0000u);
    float r2 = r1 - f1;
    a2 = (unsigned short)(__builtin_bit_cast(unsigned, r2) >> 16);
}

__device__ __forceinline__ float bfval(unsigned short v) {
    return __builtin_bit_cast(float, ((unsigned)v) << 16);
}

#define KSTEP(SK, B0_, B1_, B2_)                                                \
    {                                                                           \
        int off = ((16 * ch + (ln & 15)) << 7) +                                \
                  ((((SK << 2) + (ln >> 4)) ^ (ln & 15)) << 3);                 \
        short8v a0 = *(const short8v*)&sH0[off];                                \
        short8v a1 = *(const short8v*)&sH1[off];                                \
        short8v a2 = *(const short8v*)&sH2[off];                                \
        acc = __builtin_amdgcn_mfma_f32_16x16x32_bf16(a0, B0_, acc, 0, 0, 0);   \
        acc = __builtin_amdgcn_mfma_f32_16x16x32_bf16(a0, B1_, acc, 0, 0, 0);   \
        acc = __builtin_amdgcn_mfma_f32_16x16x32_bf16(a1, B0_, acc, 0, 0, 0);   \
        acc = __builtin_amdgcn_mfma_f32_16x16x32_bf16(a0, B2_, acc, 0, 0, 0);   \
        acc = __builtin_amdgcn_mfma_f32_16x16x32_bf16(a1, B1_, acc, 0, 0, 0);   \
        acc = __builtin_amdgcn_mfma_f32_16x16x32_bf16(a2, B0_, acc, 0, 0, 0);   \
    }

template<int NCH>
__device__ __forceinline__ void do_cell(
    int i, int jj, int b, int wv, int ln, int tid,
    const float* __restrict__ Tb, float* __restrict__ T, float* __restrict__ out,
    int* __restrict__ flgb,
    unsigned short* __restrict__ sH0, unsigned short* __restrict__ sH1,
    unsigned short* __restrict__ sH2,
    float (*part)[Ln], float* __restrict__ sER,
    const short8v (&B0)[4], const short8v (&B1)[4], const short8v (&B2)[4],
    float2 wlv, float2 wrv, float bl, float br, float bs, float wsc, float bbc)
{
    // ---- left rows are SELF-produced (previous iterations): load pre-flag ----
    float2 Lr[8], Rr[8];
    #pragma unroll
    for (int r = 0; r < 8; ++r) {
        int k = wv + 8 * r;
        int kcl = k < i ? k : i - 1;
        Lr[r] = ld_row8(Tb + ((size_t)kcl * Ln + jj) * Hd + 2 * ln);
    }

    // ---- single handoff: flag (i-1, jj+1) covers the whole right diagonal ----
    if (i >= 2) wait_flag(&flgb[(i - 1) * Ln + jj + 1]);

    #pragma unroll
    for (int r = 0; r < 8; ++r) {
        int k = wv + 8 * r;
        int kcl = k < i ? k : i - 1;
        Rr[r] = ld_row8(Tb + ((size_t)(i - 1 - kcl) * Ln + (jj + kcl + 1)) * Hd + 2 * ln);
    }
    float pl[8], pr[8];
    #pragma unroll
    for (int r = 0; r < 8; ++r) {
        pl[r] = Lr[r].x * wlv.x + Lr[r].y * wlv.y;
        pr[r] = Rr[r].x * wrv.x + Rr[r].y * wrv.y;
    }
    #pragma unroll
    for (int off2 = 32; off2 > 0; off2 >>= 1) {
        #pragma unroll
        for (int r = 0; r < 8; ++r) {
            pl[r] += __shfl_xor(pl[r], off2);
            pr[r] += __shfl_xor(pr[r], off2);
        }
    }
    #pragma unroll
    for (int r = 0; r < 8; ++r) {
        int k = wv + 8 * r;
        float sl = pl[r] + bl, sr2 = pr[r] + br;
        float mm = fmaxf(sl, sr2);
        float e0 = __expf(sl - mm), e1 = __expf(sr2 - mm);
        float inv = 1.f / (e0 + e1);
        float w0 = e0 * inv, w1 = e1 * inv;
        float h0 = w0 * Lr[r].x + w1 * Rr[r].x;
        float h1 = w0 * Lr[r].y + w1 * Rr[r].y;
        unsigned short x0, x1, x2, y0, y1, y2;
        bf_split3(h0, x0, x1, x2);
        bf_split3(h1, y0, y1, y2);
        // cols 2ln,2ln+1 -> 16B-block (ln>>2) XOR-swizzled by row
        int off = (k << 7) + ((((ln >> 2)) ^ (k & 15)) << 3) + ((2 * ln) & 7);
        *(unsigned*)&sH0[off] = (unsigned)x0 | ((unsigned)y0 << 16);
        *(unsigned*)&sH1[off] = (unsigned)x1 | ((unsigned)y1 << 16);
        *(unsigned*)&sH2[off] = (unsigned)x2 | ((unsigned)y2 << 16);
    }
    __syncthreads();

    // ---- MFMA matvec: wave owns cols [16wv,16wv+16), chunks of 16 rows ----
    const int colc = 16 * wv + (ln & 15);
    float tmp[NCH][4];
    #pragma unroll
    for (int ch = 0; ch < NCH; ++ch) {
        f32x4 acc = {0.f, 0.f, 0.f, 0.f};
        KSTEP(0, B0[0], B1[0], B2[0])
        KSTEP(1, B0[1], B1[1], B2[1])
        KSTEP(2, B0[2], B1[2], B2[2])
        KSTEP(3, B0[3], B1[3], B2[3])
        float p[4];
        #pragma unroll
        for (int q = 0; q < 4; ++q) {
            int row = 16 * ch + (ln >> 4) * 4 + q;   // C/D: col=lane&15, row=(lane>>4)*4+reg
            int offh = (row << 7) + (((colc >> 3) ^ (row & 15)) << 3) + (colc & 7);
            float h = (bfval(sH0[offh]) + bfval(sH1[offh])) + bfval(sH2[offh]); // exact
            float t = fmaxf(acc[q] + bbc, 0.f) + h;
            tmp[ch][q] = t;
            p[q] = t * wsc;
        }
        #pragma unroll
        for (int off2 = 1; off2 <= 8; off2 <<= 1) {
            #pragma unroll
            for (int q = 0; q < 4; ++q) p[q] += __shfl_xor(p[q], off2);
        }
        if ((ln & 15) == 0) {
            #pragma unroll
            for (int q = 0; q < 4; ++q)
                part[wv][16 * ch + (ln >> 4) * 4 + q] = p[q];
        }
    }
    __syncthreads();

    // ---- softmax over k (wave 0); invalid k add (64-i)*exp(bs) to denom ----
    if (wv == 0) {
        float lgv = -INFINITY;
        if (ln < i) {
            float ssum = part[0][ln];
            #pragma unroll
            for (int w = 1; w < 8; ++w) ssum += part[w][ln];
            lgv = ssum + bs;
        }
        float M = lgv;
        #pragma unroll
        for (int off2 = 32; off2 > 0; off2 >>= 1) M = fmaxf(M, __shfl_xor(M, off2));
        M = fmaxf(M, bs);
        float e = (ln < i) ? __expf(lgv - M) : 0.f;
        float S = e;
        #pragma unroll
        for (int off2 = 32; off2 > 0; off2 >>= 1) S += __shfl_xor(S, off2);
        sER[ln] = e;
        if (ln == 0) sER[64] = S + (float)(Ln - i) * __expf(bs - M);
    }
    __syncthreads();

    // ---- weighted sum over k; store result row ----
    float v = 0.f;
    #pragma unroll
    for (int ch = 0; ch < NCH; ++ch) {
        #pragma unroll
        for (int q = 0; q < 4; ++q)
            v += sER[16 * ch + (ln >> 4) * 4 + q] * tmp[ch][q];
    }
    v += __shfl_xor(v, 16);
    v += __shfl_xor(v, 32);
    if (ln < 16) {
        float res = v / sER[64];
        __hip_atomic_store(&T[(((size_t)b * Ln + i) * Ln + jj) * Hd + colc], res,
                           __ATOMIC_RELAXED, __HIP_MEMORY_SCOPE_AGENT);
        if (i == Ln - 1) out[b * Hd + colc] = res;
    }
    __syncthreads();   // per-wave vmcnt(0) before s_barrier drains result stores
    if (tid == 0)
        __hip_atomic_store(&flgb[i * Ln + jj], 1, __ATOMIC_RELAXED,
                           __HIP_MEMORY_SCOPE_AGENT);
}

__global__ __launch_bounds__(NTHR, 2)
void glt_df(const float* __restrict__ Wl, const float* __restrict__ blp,
            const float* __restrict__ Wr, const float* __restrict__ brp,
            const float* __restrict__ Wrep, const float* __restrict__ brepp,
            const float* __restrict__ Wsv, const float* __restrict__ bsp,
            float* __restrict__ T, int* __restrict__ flg, float* __restrict__ out)
{
    __shared__ __align__(16) unsigned short sH0[Ln * Hd];   // 16 KB
    __shared__ __align__(16) unsigned short sH1[Ln * Hd];   // 16 KB
    __shared__ __align__(16) unsigned short sH2[Ln * Hd];   // 16 KB
    __shared__ float part[8][Ln];                           // 2 KB
    __shared__ float sER[68];

    const int tid = threadIdx.x;
    const int wv  = tid >> 6;
    const int ln  = tid & 63;
    const int b   = blockIdx.x & 7;      // XCD round-robin: batch -> XCD
    const int p   = blockIdx.x >> 3;     // 0..63
    const int jj  = 63 - p;              // owned column; deps point to LOWER blockIdx

    if (p == 0) return;                  // column 63 has no cells

    // ---- B-fragments: Wrep cols [16wv,16wv+16) exact 3-way bf16, registers ----
    const int bcol = 16 * wv + (ln & 15);
    short8v B0[4], B1[4], B2[4];
    #pragma unroll
    for (int sk = 0; sk < 4; ++sk) {
        #pragma unroll
        for (int jx = 0; jx < 8; ++jx) {
            int k = 32 * sk + (ln >> 4) * 8 + jx;   // same k-map as A (consistent)
            float w = Wrep[k * Hd + bcol];
            unsigned short w0, w1, w2;
            bf_split3(w, w0, w1, w2);
            B0[sk][jx] = (short)w0;
            B1[sk][jx] = (short)w1;
            B2[sk][jx] = (short)w2;
        }
    }

    const float bl = blp[0], br = brp[0], bs = bsp[0];
    const float2 wlv = *(const float2*)&Wl[2 * ln];
    const float2 wrv = *(const float2*)&Wr[2 * ln];
    const float wsc = Wsv[bcol];
    const float bbc = brepp[bcol];

    const float* Tb = T + (size_t)b * (Ln * Ln * Hd);
    int* flgb = flg + b * (Ln * Ln);

    // ---- column walk: cells (i, jj) for i = 1..p ----
    for (int i = 1; i <= p; ++i) {
        switch ((i + 15) >> 4) {
            case 1: do_cell<1>(i, jj, b, wv, ln, tid, Tb, T, out, flgb,
                               sH0, sH1, sH2, part, sER, B0, B1, B2,
                               wlv, wrv, bl, br, bs, wsc, bbc); break;
            case 2: do_cell<2>(i, jj, b, wv, ln, tid, Tb, T, out, flgb,
                               sH0, sH1, sH2, part, sER, B0, B1, B2,
                               wlv, wrv, bl, br, bs, wsc, bbc); break;
            case 3: do_cell<3>(i, jj, b, wv, ln, tid, Tb, T, out, flgb,
                               sH0, sH1, sH2, part, sER, B0, B1, B2,
                               wlv, wrv, bl, br, bs, wsc, bbc); break;
            default: do_cell<4>(i, jj, b, wv, ln, tid, Tb, T, out, flgb,
                                sH0, sH1, sH2, part, sER, B0, B1, B2,
                                wlv, wrv, bl, br, bs, wsc, bbc); break;
        }
    }
}

extern "C" void kernel_launch(void* const* d_in, const int* in_sizes, int n_in,
                              void* d_out, int out_size, void* d_ws, size_t ws_size,
                              hipStream_t stream)
{
    const float* wf   = (const float*)d_in[0];
    const float* Wl   = (const float*)d_in[2];
    const float* bl   = (const float*)d_in[3];
    const float* Wr   = (const float*)d_in[4];
    const float* br   = (const float*)d_in[5];
    const float* Wrep = (const float*)d_in[6];
    const float* brep = (const float*)d_in[7];
    const float* Ws   = (const float*)d_in[8];
    const float* bs   = (const float*)d_in[9];

    float* T   = (float*)d_ws;                                   // 16 MB
    int*   flg = (int*)((char*)d_ws + (size_t)Bsz * Ln * Ln * Hd * 4);
    float* out = (float*)d_out;

    init_kernel<<<256, 256, 0, stream>>>(wf, T, flg);
    glt_df<<<NBLK, NTHR, 0, stream>>>(Wl, bl, Wr, br, Wrep, brep, Ws, bs,
                                      T, flg, out);
}